// Round 16
// baseline (242.409 us; speedup 1.0000x reference)
//
#include <hip/hip_runtime.h>
#include <cstdint>
#include <cstddef>

// ---------- types ----------
typedef __attribute__((ext_vector_type(4))) float f32x4;

typedef const __attribute__((address_space(1))) void gv_t;
typedef __attribute__((address_space(3))) void lv_t;
#define GLL16(gsrc, ldst) __builtin_amdgcn_global_load_lds((gv_t*)(gsrc), (lv_t*)(ldst), 16, 0, 0)

// fp8 e4m3 (OCP) helpers — op_sel must be a literal constant -> template param
template<bool HI>
__device__ __forceinline__ unsigned pk_fp8(float a, float b, unsigned old){
  return (unsigned)__builtin_amdgcn_cvt_pk_fp8_f32(a, b, (int)old, HI);
}
__device__ __forceinline__ uint2 pack8_fp8(const float* v){
  unsigned lo = pk_fp8<false>(v[0], v[1], 0u);
  lo = pk_fp8<true>(v[2], v[3], lo);
  unsigned hi = pk_fp8<false>(v[4], v[5], 0u);
  hi = pk_fp8<true>(v[6], v[7], hi);
  return make_uint2(lo, hi);
}
__device__ __forceinline__ unsigned short f2bf(float f){
  unsigned u = __builtin_bit_cast(unsigned, f);
  u += 0x7fffu + ((u >> 16) & 1u);
  return (unsigned short)(u >> 16);
}
__device__ __forceinline__ float bf2f(unsigned short h){
  unsigned u = ((unsigned)h) << 16;
  return __builtin_bit_cast(float, u);
}

// Problem constants: B=128, C=1280, N=256 tokens, BD=256, NH=4, HD=64, NQ=21, NJ=16
// W scale: Wb stores fp8(16*g*w); img staged as fp8(x); gemm acc scaled by 1/16.

// ---------- kernel 1: W prep (plain layout) ----------
__global__ __launch_bounds__(512) void prep_w(const float* __restrict__ wk, const float* __restrict__ wv,
                                              const float* __restrict__ g, const float* __restrict__ bl,
                                              unsigned char* __restrict__ Wb, float* __restrict__ uvP){
  int dd = threadIdx.x;           // 0..511  (0..255 -> K, 256..511 -> V)
  int cs = blockIdx.x;            // 16 chunks of 80 channels
  const float* w = (dd < 256) ? (wk + dd) : (wv + (dd - 256));
  float uu = 0.f, vv = 0.f;
  for (int cb = 0; cb < 80; cb += 8){
    int c0 = cs * 80 + cb;
    float tmp[8];
    #pragma unroll
    for (int i = 0; i < 8; ++i){
      int c = c0 + i;
      float wc = w[(size_t)c * 256];
      float gw = g[c] * wc;
      uu += gw;
      vv += bl[c] * wc;
      tmp[i] = 16.f * gw;
    }
    uint2 pk = pack8_fp8(tmp);
    *(uint2*)(Wb + ((size_t)(c0 >> 3) * 512 + dd) * 8) = pk;
  }
  uvP[(cs * 2 + 0) * 512 + dd] = uu;
  uvP[(cs * 2 + 1) * 512 + dd] = vv;
}

__global__ __launch_bounds__(512) void reduce_uv(const float* __restrict__ uvP,
                                                 const float* __restrict__ bk, const float* __restrict__ bv,
                                                 float* __restrict__ u, float* __restrict__ v){
  int dd = threadIdx.x;
  float su = 0.f, sv = 0.f;
  #pragma unroll
  for (int cs = 0; cs < 16; ++cs){
    su += uvP[(cs * 2 + 0) * 512 + dd];
    sv += uvP[(cs * 2 + 1) * 512 + dd];
  }
  u[dd] = su;
  v[dd] = sv + ((dd < 256) ? bk[dd] : bv[dd - 256]);
}

// ---------- kernel 2: transposing img->fp8 converter (verified in r11) ----------
// Block = (batch, 64-channel chunk). Reads: wave-level 1KB-contiguous float4 rows.
// Writes: Xb[b_local][c/8][n][8] fp8, 2x32B contiguous per thread. Reg-only transpose.
__global__ __launch_bounds__(256) void pass1t(const float* __restrict__ img, unsigned char* __restrict__ Xb,
                                              float* __restrict__ sumsP, int b0){
  __shared__ float sl[256][4][2];
  int blk = blockIdx.x;
  int bl = blk / 20, cs = blk % 20;
  int bg = b0 + bl;
  int t = threadIdx.x;
  int nq = t & 63, rg = t >> 6;
  const float* src = img + (size_t)bg*1280*256 + (size_t)(cs*64 + rg*16)*256 + nq*4;
  unsigned q[16];
  float s[4] = {0.f,0.f,0.f,0.f}, s2[4] = {0.f,0.f,0.f,0.f};
  #pragma unroll
  for (int k = 0; k < 16; ++k){
    f32x4 vv = *(const f32x4*)(src + (size_t)k*256);
    #pragma unroll
    for (int i = 0; i < 4; ++i){ s[i] += vv[i]; s2[i] += vv[i]*vv[i]; }
    unsigned lo = pk_fp8<false>(vv.x, vv.y, 0u);
    q[k] = pk_fp8<true>(vv.z, vv.w, lo);
  }
  #pragma unroll
  for (int o = 0; o < 2; ++o){
    size_t kb = (size_t)(bl*160 + cs*8 + rg*2 + o);
    #pragma unroll
    for (int i = 0; i < 4; ++i){
      unsigned lo = 0, hi = 0;
      #pragma unroll
      for (int j = 0; j < 4; ++j){
        lo |= ((q[o*8 + j]     >> (8*i)) & 0xffu) << (8*j);
        hi |= ((q[o*8 + 4 + j] >> (8*i)) & 0xffu) << (8*j);
      }
      *(uint2*)(Xb + (kb*256 + nq*4 + i)*8) = make_uint2(lo, hi);
    }
  }
  #pragma unroll
  for (int i = 0; i < 4; ++i){ sl[nq*4 + i][rg][0] = s[i]; sl[nq*4 + i][rg][1] = s2[i]; }
  __syncthreads();
  {
    int n = t;
    float ss  = sl[n][0][0] + sl[n][1][0] + sl[n][2][0] + sl[n][3][0];
    float ss2 = sl[n][0][1] + sl[n][1][1] + sl[n][2][1] + sl[n][3][1];
    sumsP[((size_t)(bg*256 + n)*20 + cs)*2 + 0] = ss;
    sumsP[((size_t)(bg*256 + n)*20 + cs)*2 + 1] = ss2;
  }
}

// ---------- kernel 2b: fold 20 chunk-partials -> per-token mean/rstd ----------
__global__ __launch_bounds__(256) void statsk(const float* __restrict__ sumsP, float* __restrict__ mr, int b0){
  int bg = b0 + blockIdx.x;
  int n = threadIdx.x;
  const float* p = sumsP + (size_t)(bg*256 + n)*40;
  float s = 0.f, s2 = 0.f;
  #pragma unroll
  for (int i = 0; i < 20; ++i){ s += p[2*i]; s2 += p[2*i + 1]; }
  float m = s * (1.f/1280.f);
  float var = s2 * (1.f/1280.f) - m*m;
  mr[((size_t)bg*256 + n)*2 + 0] = m;
  mr[((size_t)bg*256 + n)*2 + 1] = rsqrtf(var + 1e-5f);
}

// ---------- kernel 3: joint embed + Q projection (1024 threads) ----------
__global__ __launch_bounds__(1024) void jointk(const float* __restrict__ joints, const float* __restrict__ pcam,
    const float* __restrict__ focal,
    const float* __restrict__ jw1, const float* __restrict__ jb1,
    const float* __restrict__ jw2, const float* __restrict__ jb2,
    const float* __restrict__ jid, const float* __restrict__ wq, const float* __restrict__ bq,
    float* __restrict__ Jf, float* __restrict__ Qw, float* __restrict__ J2){
  __shared__ float ji[21][5];
  __shared__ float hid[21][256];
  __shared__ float jfs[21][256];
  int b = blockIdx.x, t = threadIdx.x;
  int col = t & 255, grp = t >> 8;
  if (t < 21){
    float sc = pcam[b*3], tx = pcam[b*3+1], ty = pcam[b*3+2];
    float f0 = focal[b*2], f1 = focal[b*2+1];
    float tz = 2.f * f0 / (256.f * sc + 1e-9f);
    const float* jp = joints + (size_t)(b*21 + t) * 3;
    float jx = jp[0], jy = jp[1], jz = jp[2];
    float cx = jx + tx, cy = jy + ty, cz = jz + tz;
    float zz = fmaxf(cz, 1e-6f);
    float nx = (cx / zz) * f0 * (1.f/128.f);
    float ny = (cy / zz) * f1 * (1.f/128.f);
    ji[t][0]=jx; ji[t][1]=jy; ji[t][2]=jz; ji[t][3]=nx; ji[t][4]=ny;
    J2[(b*21 + t)*2 + 0] = nx;
    J2[(b*21 + t)*2 + 1] = ny;
  }
  __syncthreads();
  float w1v[5];
  #pragma unroll
  for (int i = 0; i < 5; ++i) w1v[i] = jw1[i*256 + col];
  float b1v = jb1[col];
  #pragma unroll
  for (int jj = 0; jj < 6; ++jj){
    int q = grp + 4*jj;
    if (q < 21){
      float h = b1v;
      #pragma unroll
      for (int i = 0; i < 5; ++i) h += ji[q][i] * w1v[i];
      hid[q][col] = fmaxf(h, 0.f);
    }
  }
  __syncthreads();
  float accq[6];
  float b2v = jb2[col];
  #pragma unroll
  for (int jj = 0; jj < 6; ++jj){
    int q = grp + 4*jj;
    accq[jj] = (q < 21) ? b2v + jid[q*256 + col] : 0.f;
  }
  for (int k = 0; k < 256; k += 4){
    float w0 = jw2[(k+0)*256 + col], w1 = jw2[(k+1)*256 + col];
    float w2 = jw2[(k+2)*256 + col], w3 = jw2[(k+3)*256 + col];
    #pragma unroll
    for (int jj = 0; jj < 6; ++jj){
      int q = grp + 4*jj;
      if (q < 21){
        f32x4 hv = *(const f32x4*)&hid[q][k];
        accq[jj] += hv.x*w0 + hv.y*w1 + hv.z*w2 + hv.w*w3;
      }
    }
  }
  #pragma unroll
  for (int jj = 0; jj < 6; ++jj){
    int q = grp + 4*jj;
    if (q < 21){ jfs[q][col] = accq[jj]; Jf[(size_t)b*5376 + q*256 + col] = accq[jj]; }
  }
  __syncthreads();
  float bqv = bq[col];
  #pragma unroll
  for (int jj = 0; jj < 6; ++jj) accq[jj] = bqv;
  for (int k = 0; k < 256; k += 4){
    float w0 = wq[(k+0)*256 + col], w1 = wq[(k+1)*256 + col];
    float w2 = wq[(k+2)*256 + col], w3 = wq[(k+3)*256 + col];
    #pragma unroll
    for (int jj = 0; jj < 6; ++jj){
      int q = grp + 4*jj;
      if (q < 21){
        f32x4 hv = *(const f32x4*)&jfs[q][k];
        accq[jj] += hv.x*w0 + hv.y*w1 + hv.z*w2 + hv.w*w3;
      }
    }
  }
  #pragma unroll
  for (int jj = 0; jj < 6; ++jj){
    int q = grp + 4*jj;
    if (q < 21) Qw[(size_t)b*5376 + q*256 + col] = accq[jj];
  }
}

// ---------- kernel 4: K/V GEMM — register-direct, BARRIER-FREE, LDS-FREE ----------
// Pre-packed fp8 operands make MFMA fragments 8B-contiguous in global memory:
// each lane global_load_dwordx2's its fragment straight to registers. No __syncthreads.
// Block = (batch, m-half, n-quarter): 4 waves, wave tile 64x64, 40 iters x {8 loads + 16 MFMA}.
__global__ __launch_bounds__(256) void gemm_kv(const unsigned char* __restrict__ Wb,
    const unsigned char* __restrict__ Xb,
    const float* __restrict__ mr, const float* __restrict__ u, const float* __restrict__ v,
    unsigned short* __restrict__ Kt, unsigned short* __restrict__ Vn, int b0){
  int blk = blockIdx.x;
  int bl = blk >> 3, sub = blk & 7;
  int mh = sub >> 2, nq = sub & 3;
  int bg = b0 + bl;
  int lane = threadIdx.x & 63, wid = threadIdx.x >> 6;   // 4 waves = 4 m-quarters
  int g = lane >> 4, r = lane & 15;
  int mbase = mh*256 + wid*64;        // dd base of this wave (0..448)
  int nbase = nq*64;                  // n base (0..192)
  const unsigned char* Ab = Wb;                          // [kb 160][dd 512][8]
  const unsigned char* Bb = Xb + (size_t)bl*160*256*8;   // [kb 160][n 256][8]

  f32x4 acc[4][4];
  #pragma unroll
  for (int i = 0; i < 4; ++i)
    #pragma unroll
    for (int j = 0; j < 4; ++j) acc[i][j] = f32x4{0.f,0.f,0.f,0.f};

  #pragma unroll 4
  for (int kq = 0; kq < 40; ++kq){
    int kb = kq*4 + g;                 // this lane-group's 8-channel oct
    long av[4], bv[4];
    #pragma unroll
    for (int m = 0; m < 4; ++m)
      av[m] = *(const long*)(Ab + ((size_t)kb*512 + mbase + m*16 + r)*8);
    #pragma unroll
    for (int nn = 0; nn < 4; ++nn)
      bv[nn] = *(const long*)(Bb + ((size_t)kb*256 + nbase + nn*16 + r)*8);
    #pragma unroll
    for (int m = 0; m < 4; ++m)
      #pragma unroll
      for (int nn = 0; nn < 4; ++nn)
        acc[m][nn] = __builtin_amdgcn_mfma_f32_16x16x32_fp8_fp8(av[m], bv[nn], acc[m][nn], 0, 0, 0);
  }

  // epilogue: LN fold with precomputed mean/rstd -> bf16 K/V
  int b256l = bl * 256;
  float mean[4], rstd[4];
  #pragma unroll
  for (int nn = 0; nn < 4; ++nn){
    int n = nbase + nn*16 + r;
    mean[nn] = mr[((size_t)bg*256 + n)*2 + 0];
    rstd[nn] = mr[((size_t)bg*256 + n)*2 + 1];
  }
  #pragma unroll
  for (int m = 0; m < 4; ++m){
    #pragma unroll
    for (int reg = 0; reg < 4; ++reg){
      int dd = mbase + m*16 + g*4 + reg;
      float uu = u[dd], vv = v[dd];
      #pragma unroll
      for (int nn = 0; nn < 4; ++nn){
        int n = nbase + nn*16 + r;
        float val = rstd[nn] * (acc[m][nn][reg] * 0.0625f - mean[nn] * uu) + vv;
        unsigned short hbf = f2bf(val);
        if (dd < 256) Kt[(size_t)(b256l + dd) * 256 + n] = hbf;          // K: d-major
        else          Vn[(size_t)(b256l + n) * 256 + (dd - 256)] = hbf;  // V: n-major
      }
    }
  }
}

// ---------- kernel 5: attention (bf16 K/V; XCD-swizzled) ----------
__global__ __launch_bounds__(256) void attnk(const float* __restrict__ Qw, const unsigned short* __restrict__ Kt,
    const unsigned short* __restrict__ Vn, const float* __restrict__ J2, float* __restrict__ AO, int b0){
  __shared__ float Qs[21][64];
  __shared__ float Ls[21][256];
  __shared__ float j2s[21][2];
  int blk = blockIdx.x;
  int xcd = blk & 7, p = blk >> 3;
  int h = p & 3;
  int bl = (p >> 2) * 8 + xcd;
  int bg = b0 + bl;
  int t = threadIdx.x;
  for (int i = t; i < 21*64; i += 256){
    int q = i >> 6, d = i & 63;
    Qs[q][d] = 0.125f * Qw[(size_t)(bg*21 + q) * 256 + h*64 + d];
  }
  if (t < 42) ((float*)j2s)[t] = J2[bg*42 + t];
  __syncthreads();

  int n = t;
  float xn = (float)(n & 15) * 0.125f - 0.9375f;
  float yn = (float)(n >> 4) * 0.125f - 0.9375f;
  float l[21];
  #pragma unroll
  for (int q = 0; q < 21; ++q){
    float dx = j2s[q][0] - xn, dy = j2s[q][1] - yn;
    l[q] = -(dx*dx + dy*dy) * (1.f/0.72f);
  }
  const unsigned short* Kp = Kt + ((size_t)(bl*256) + h*64) * 256 + n;
  for (int d = 0; d < 64; d += 4){
    float k0 = bf2f(Kp[(size_t)(d+0)*256]);
    float k1 = bf2f(Kp[(size_t)(d+1)*256]);
    float k2 = bf2f(Kp[(size_t)(d+2)*256]);
    float k3 = bf2f(Kp[(size_t)(d+3)*256]);
    #pragma unroll
    for (int q = 0; q < 21; ++q){
      f32x4 qv = *(const f32x4*)&Qs[q][d];
      l[q] += qv.x*k0 + qv.y*k1 + qv.z*k2 + qv.w*k3;
    }
  }
  #pragma unroll
  for (int q = 0; q < 21; ++q) Ls[q][n] = l[q];
  __syncthreads();

  int wv_ = t >> 6, lane = t & 63;
  for (int q = wv_; q < 21; q += 4){
    float v0 = Ls[q][lane], v1 = Ls[q][lane+64], v2 = Ls[q][lane+128], v3 = Ls[q][lane+192];
    float mx = fmaxf(fmaxf(v0, v1), fmaxf(v2, v3));
    #pragma unroll
    for (int off = 32; off >= 1; off >>= 1) mx = fmaxf(mx, __shfl_xor(mx, off));
    float e0 = __expf(v0 - mx), e1 = __expf(v1 - mx), e2 = __expf(v2 - mx), e3 = __expf(v3 - mx);
    float ss = e0 + e1 + e2 + e3;
    #pragma unroll
    for (int off = 32; off >= 1; off >>= 1) ss += __shfl_xor(ss, off);
    float inv = 1.f / ss;
    Ls[q][lane] = e0*inv; Ls[q][lane+64] = e1*inv; Ls[q][lane+128] = e2*inv; Ls[q][lane+192] = e3*inv;
  }
  __syncthreads();

  int d = t & 63, grp = t >> 6;
  const unsigned short* Vp = Vn + (size_t)(bl*256) * 256 + h*64 + d;
  float aq[6] = {0.f,0.f,0.f,0.f,0.f,0.f};
  for (int n2b = 0; n2b < 256; n2b += 32){
    float vdec[32];
    #pragma unroll
    for (int i = 0; i < 32; ++i) vdec[i] = bf2f(Vp[(size_t)(n2b + i) * 256]);
    #pragma unroll
    for (int j = 0; j < 6; ++j){
      int q = grp + 4*j;
      if (q < 21){
        float sacc = 0.f;
        #pragma unroll
        for (int i = 0; i < 32; ++i) sacc += Ls[q][n2b + i] * vdec[i];
        aq[j] += sacc;
      }
    }
  }
  #pragma unroll
  for (int j = 0; j < 6; ++j){
    int q = grp + 4*j;
    if (q < 21) AO[(size_t)(bg*21 + q) * 256 + h*64 + d] = aq[j];
  }
}

// ---------- kernel 6: out-proj + LN + decoder heads (1024 threads) ----------
__global__ __launch_bounds__(1024) void headk(const float* __restrict__ AO, const float* __restrict__ Jf,
    const float* __restrict__ wo, const float* __restrict__ bo,
    const float* __restrict__ ng, const float* __restrict__ nb_,
    const float* __restrict__ dpw, const float* __restrict__ dpb,
    const float* __restrict__ dsw, const float* __restrict__ dsb,
    const float* __restrict__ dcw, const float* __restrict__ dcb,
    const float* __restrict__ pls, const float* __restrict__ bls, const float* __restrict__ cls,
    const float* __restrict__ prot, const float* __restrict__ betas, const float* __restrict__ cam,
    float* __restrict__ out){
  __shared__ float AOs[21][256];
  __shared__ float Os[21][256];
  __shared__ float mst[21], rst[21];
  __shared__ float pp[21][48];
  __shared__ float dp[48];
  __shared__ float mb[256];
  int b = blockIdx.x, t = threadIdx.x;
  int col = t & 255, grp = t >> 8;
  for (int i = t; i < 5376; i += 1024) ((float*)AOs)[i] = AO[(size_t)b*5376 + i];
  __syncthreads();

  float accq[6];
  float bov = bo[col];
  #pragma unroll
  for (int jj = 0; jj < 6; ++jj){
    int q = grp + 4*jj;
    accq[jj] = (q < 21) ? bov + Jf[(size_t)b*5376 + q*256 + col] : 0.f;
  }
  for (int k = 0; k < 256; k += 4){
    float w0 = wo[(k+0)*256 + col], w1 = wo[(k+1)*256 + col];
    float w2 = wo[(k+2)*256 + col], w3 = wo[(k+3)*256 + col];
    #pragma unroll
    for (int jj = 0; jj < 6; ++jj){
      int q = grp + 4*jj;
      if (q < 21){
        f32x4 av = *(const f32x4*)&AOs[q][k];
        accq[jj] += av.x*w0 + av.y*w1 + av.z*w2 + av.w*w3;
      }
    }
  }
  #pragma unroll
  for (int jj = 0; jj < 6; ++jj){
    int q = grp + 4*jj;
    if (q < 21) Os[q][col] = accq[jj];
  }
  __syncthreads();

  int w = t >> 6, lane = t & 63;
  for (int q = w; q < 21; q += 16){
    float v0 = Os[q][lane], v1 = Os[q][lane+64], v2 = Os[q][lane+128], v3 = Os[q][lane+192];
    float s = v0+v1+v2+v3;
    float s2 = v0*v0+v1*v1+v2*v2+v3*v3;
    #pragma unroll
    for (int off = 32; off >= 1; off >>= 1){ s += __shfl_xor(s, off); s2 += __shfl_xor(s2, off); }
    if (lane == 0){
      float m = s * (1.f/256.f);
      float var = s2 * (1.f/256.f) - m*m;
      mst[q] = m; rst[q] = rsqrtf(var + 1e-5f);
    }
  }
  __syncthreads();

  float gg = ng[col], bb = nb_[col];
  #pragma unroll
  for (int jj = 0; jj < 6; ++jj){
    int q = grp + 4*jj;
    if (q < 21) Os[q][col] = (accq[jj] - mst[q]) * rst[q] * gg + bb;
  }
  __syncthreads();

  if (t < 256){
    float s = 0.f;
    #pragma unroll
    for (int q = 0; q < 21; ++q) s += Os[q][t];
    mb[t] = s * (1.f/21.f);
  }
  if (t < 1008){
    int q = t / 48, j = t % 48;
    float a = 0.f;
    for (int k = 0; k < 256; k += 4){
      f32x4 ov = *(const f32x4*)&Os[q][k];
      const float* wp = dpw + (size_t)(q*256 + k) * 48 + j;
      a += ov.x*wp[0] + ov.y*wp[48] + ov.z*wp[96] + ov.w*wp[144];
    }
    pp[q][j] = a;
  }
  __syncthreads();

  float e_p = __expf(pls[0]), e_b = __expf(bls[0]), e_c = __expf(cls[0]);
  if (t < 48){
    float a = dpb[t];
    #pragma unroll
    for (int q = 0; q < 21; ++q) a += pp[q][t];
    dp[t] = a * e_p;
  }
  __syncthreads();

  if (t < 16){
    int j = t;
    float ax = dp[3*j], ay = dp[3*j+1], az = dp[3*j+2];
    float ang = sqrtf(ax*ax + ay*ay + az*az + 1e-16f);
    float inv = 1.f / ang;
    float x = ax*inv, y = ay*inv, z = az*inv;
    float s_ = sinf(ang), c_ = cosf(ang), mc = 1.f - c_;
    float R00 = 1.f - mc*(y*y + z*z), R01 = -s_*z + mc*x*y,      R02 = s_*y + mc*x*z;
    float R10 = s_*z + mc*x*y,        R11 = 1.f - mc*(x*x + z*z), R12 = -s_*x + mc*y*z;
    float R20 = -s_*y + mc*x*z,       R21 = s_*x + mc*y*z,        R22 = 1.f - mc*(x*x + y*y);
    const float* P = prot + (size_t)(b*16 + j) * 9;
    float p0=P[0],p1=P[1],p2=P[2],p3=P[3],p4=P[4],p5=P[5],p6=P[6],p7=P[7],p8=P[8];
    float* o = out + (size_t)(b*16 + j) * 9;
    o[0]=R00*p0 + R01*p3 + R02*p6; o[1]=R00*p1 + R01*p4 + R02*p7; o[2]=R00*p2 + R01*p5 + R02*p8;
    o[3]=R10*p0 + R11*p3 + R12*p6; o[4]=R10*p1 + R11*p4 + R12*p7; o[5]=R10*p2 + R11*p5 + R12*p8;
    o[6]=R20*p0 + R21*p3 + R22*p6; o[7]=R20*p1 + R21*p4 + R22*p7; o[8]=R20*p2 + R21*p5 + R22*p8;
  }
  if (w >= 4 && w < 14){
    int j = w - 4;
    float a = 0.f;
    #pragma unroll
    for (int i = 0; i < 4; ++i){
      int k = lane + 64*i;
      a += mb[k] * dsw[k*10 + j];
    }
    #pragma unroll
    for (int off = 32; off >= 1; off >>= 1) a += __shfl_xor(a, off);
    if (lane == 0) out[18432 + b*10 + j] = betas[b*10 + j] + (a + dsb[j]) * e_b;
  }
  if (w >= 1 && w < 4){
    int j = w - 1;
    float a = 0.f;
    #pragma unroll
    for (int i = 0; i < 4; ++i){
      int k = lane + 64*i;
      a += Os[0][k] * dcw[k*3 + j];
    }
    #pragma unroll
    for (int off = 32; off >= 1; off >>= 1) a += __shfl_xor(a, off);
    if (lane == 0) out[19712 + b*3 + j] = cam[b*3 + j] + (a + dcb[j]) * e_c;
  }
}

// ---------- launch ----------
extern "C" void kernel_launch(void* const* d_in, const int* in_sizes, int n_in,
                              void* d_out, int out_size, void* d_ws, size_t ws_size,
                              hipStream_t stream) {
  const float* img    = (const float*)d_in[0];
  const float* joints = (const float*)d_in[1];
  const float* pcam   = (const float*)d_in[2];
  const float* focal  = (const float*)d_in[3];
  const float* prot   = (const float*)d_in[4];
  const float* betas  = (const float*)d_in[5];
  const float* cam    = (const float*)d_in[6];
  const float* ln_g   = (const float*)d_in[7];
  const float* ln_b   = (const float*)d_in[8];
  const float* wk     = (const float*)d_in[9];
  const float* bk     = (const float*)d_in[10];
  const float* wv     = (const float*)d_in[11];
  const float* bv     = (const float*)d_in[12];
  const float* jw1    = (const float*)d_in[13];
  const float* jb1    = (const float*)d_in[14];
  const float* jw2    = (const float*)d_in[15];
  const float* jb2    = (const float*)d_in[16];
  const float* jid    = (const float*)d_in[17];
  const float* wq     = (const float*)d_in[18];
  const float* bq     = (const float*)d_in[19];
  const float* wo     = (const float*)d_in[20];
  const float* bo     = (const float*)d_in[21];
  const float* ng     = (const float*)d_in[22];
  const float* nb     = (const float*)d_in[23];
  const float* dpw    = (const float*)d_in[24];
  const float* dpb    = (const float*)d_in[25];
  const float* dsw    = (const float*)d_in[26];
  const float* dsb    = (const float*)d_in[27];
  const float* dcw    = (const float*)d_in[28];
  const float* dcb    = (const float*)d_in[29];
  const float* pls    = (const float*)d_in[30];
  const float* bls    = (const float*)d_in[31];
  const float* cls    = (const float*)d_in[32];

  // Fixed region, then batch-chunked Xb (fp8) + Kt/Vn (bf16).
  char* ws = (char*)d_ws;
  float*         uvP   = (float*)(ws + 0);                //    65,536
  float*         u     = (float*)(ws + 65536);            //     2,048
  float*         v     = (float*)(ws + 67584);            //     2,048
  unsigned char* Wb    = (unsigned char*)(ws + 69632);    //   655,360
  float*         Jf    = (float*)(ws + 724992);           // 2,752,512
  float*         Qw    = (float*)(ws + 3477504);          // 2,752,512
  float*         J2    = (float*)(ws + 6230016);          //    21,504
  float*         AO    = (float*)(ws + 6251520);          // 2,752,512
  float*         sumsP = (float*)(ws + 9004032);          // 5,242,880
  float*         mr    = (float*)(ws + 14246912);         //   262,144
  const size_t FIXED = 14509056;

  // chunked: Xb 41,943,040 + Kt 16,777,216 + Vn 16,777,216 = 75,497,472 total
  int NC = 16;
  for (int c = 1; c <= 16; c <<= 1){
    size_t need = FIXED + (size_t)75497472 / c;
    if (need <= ws_size){ NC = c; break; }
  }
  int Bc = 128 / NC;
  size_t xb_bytes = (size_t)41943040 / NC;
  size_t kv_bytes = (size_t)16777216 / NC;
  unsigned char*  Xb = (unsigned char*)(ws + FIXED);
  unsigned short* Kt = (unsigned short*)(ws + FIXED + xb_bytes);
  unsigned short* Vn = (unsigned short*)(ws + FIXED + xb_bytes + kv_bytes);

  float* out = (float*)d_out;  // f32 outputs

  prep_w   <<<16,  512, 0, stream>>>(wk, wv, ln_g, ln_b, Wb, uvP);
  reduce_uv<<<1,   512, 0, stream>>>(uvP, bk, bv, u, v);
  jointk   <<<128, 1024, 0, stream>>>(joints, pcam, focal, jw1, jb1, jw2, jb2, jid, wq, bq, Jf, Qw, J2);
  for (int c = 0; c < NC; ++c){
    int b0 = c * Bc;
    pass1t  <<<Bc*20, 256, 0, stream>>>(img, Xb, sumsP, b0);
    statsk  <<<Bc,    256, 0, stream>>>(sumsP, mr, b0);
    gemm_kv <<<Bc*8,  256, 0, stream>>>(Wb, Xb, mr, u, v, Kt, Vn, b0);
    attnk   <<<Bc*4,  256, 0, stream>>>(Qw, Kt, Vn, J2, AO, b0);
  }
  headk    <<<128, 1024, 0, stream>>>(AO, Jf, wo, bo, ng, nb, dpw, dpb, dsw, dsb, dcw, dcb, pls, bls, cls, prot, betas, cam, out);
}

// Round 17
// 171.229 us; speedup vs baseline: 1.4157x; 1.4157x over previous
//
#include <hip/hip_runtime.h>
#include <cstdint>
#include <cstddef>

// ---------- types ----------
typedef __attribute__((ext_vector_type(4))) float f32x4;

typedef const __attribute__((address_space(1))) void gv_t;
typedef __attribute__((address_space(3))) void lv_t;
#define GLL16(gsrc, ldst) __builtin_amdgcn_global_load_lds((gv_t*)(gsrc), (lv_t*)(ldst), 16, 0, 0)

// fp8 e4m3 (OCP) helpers — op_sel must be a literal constant -> template param
template<bool HI>
__device__ __forceinline__ unsigned pk_fp8(float a, float b, unsigned old){
  return (unsigned)__builtin_amdgcn_cvt_pk_fp8_f32(a, b, (int)old, HI);
}
__device__ __forceinline__ uint2 pack8_fp8(const float* v){
  unsigned lo = pk_fp8<false>(v[0], v[1], 0u);
  lo = pk_fp8<true>(v[2], v[3], lo);
  unsigned hi = pk_fp8<false>(v[4], v[5], 0u);
  hi = pk_fp8<true>(v[6], v[7], hi);
  return make_uint2(lo, hi);
}
__device__ __forceinline__ unsigned short f2bf(float f){
  unsigned u = __builtin_bit_cast(unsigned, f);
  u += 0x7fffu + ((u >> 16) & 1u);
  return (unsigned short)(u >> 16);
}
__device__ __forceinline__ float bf2f(unsigned short h){
  unsigned u = ((unsigned)h) << 16;
  return __builtin_bit_cast(float, u);
}

// Problem constants: B=128, C=1280, N=256 tokens, BD=256, NH=4, HD=64, NQ=21, NJ=16
// W scale: Wb stores fp8(16*g*w); img staged as fp8(x); gemm acc scaled by 1/16.

// ---------- kernel 1: W prep (plain layout) ----------
__global__ __launch_bounds__(512) void prep_w(const float* __restrict__ wk, const float* __restrict__ wv,
                                              const float* __restrict__ g, const float* __restrict__ bl,
                                              unsigned char* __restrict__ Wb, float* __restrict__ uvP){
  int dd = threadIdx.x;           // 0..511  (0..255 -> K, 256..511 -> V)
  int cs = blockIdx.x;            // 16 chunks of 80 channels
  const float* w = (dd < 256) ? (wk + dd) : (wv + (dd - 256));
  float uu = 0.f, vv = 0.f;
  for (int cb = 0; cb < 80; cb += 8){
    int c0 = cs * 80 + cb;
    float tmp[8];
    #pragma unroll
    for (int i = 0; i < 8; ++i){
      int c = c0 + i;
      float wc = w[(size_t)c * 256];
      float gw = g[c] * wc;
      uu += gw;
      vv += bl[c] * wc;
      tmp[i] = 16.f * gw;
    }
    uint2 pk = pack8_fp8(tmp);
    *(uint2*)(Wb + ((size_t)(c0 >> 3) * 512 + dd) * 8) = pk;
  }
  uvP[(cs * 2 + 0) * 512 + dd] = uu;
  uvP[(cs * 2 + 1) * 512 + dd] = vv;
}

// ---------- kernel 3: joint embed + Q projection (1024 threads) + folded reduce_uv ----------
__global__ __launch_bounds__(1024) void jointk(const float* __restrict__ joints, const float* __restrict__ pcam,
    const float* __restrict__ focal,
    const float* __restrict__ jw1, const float* __restrict__ jb1,
    const float* __restrict__ jw2, const float* __restrict__ jb2,
    const float* __restrict__ jid, const float* __restrict__ wq, const float* __restrict__ bq,
    const float* __restrict__ uvP, const float* __restrict__ bk, const float* __restrict__ bv,
    float* __restrict__ u, float* __restrict__ v,
    float* __restrict__ Jf, float* __restrict__ Qw, float* __restrict__ J2){
  __shared__ float ji[21][5];
  __shared__ float hid[21][256];
  __shared__ float jfs[21][256];
  int b = blockIdx.x, t = threadIdx.x;
  int col = t & 255, grp = t >> 8;
  // folded reduce_uv: block 0 threads 0..511 write u,v (consumed by gemm, launched later)
  if (b == 0 && t < 512){
    float su = 0.f, sv = 0.f;
    #pragma unroll
    for (int cs = 0; cs < 16; ++cs){
      su += uvP[(cs * 2 + 0) * 512 + t];
      sv += uvP[(cs * 2 + 1) * 512 + t];
    }
    u[t] = su;
    v[t] = sv + ((t < 256) ? bk[t] : bv[t - 256]);
  }
  if (t < 21){
    float sc = pcam[b*3], tx = pcam[b*3+1], ty = pcam[b*3+2];
    float f0 = focal[b*2], f1 = focal[b*2+1];
    float tz = 2.f * f0 / (256.f * sc + 1e-9f);
    const float* jp = joints + (size_t)(b*21 + t) * 3;
    float jx = jp[0], jy = jp[1], jz = jp[2];
    float cx = jx + tx, cy = jy + ty, cz = jz + tz;
    float zz = fmaxf(cz, 1e-6f);
    float nx = (cx / zz) * f0 * (1.f/128.f);
    float ny = (cy / zz) * f1 * (1.f/128.f);
    ji[t][0]=jx; ji[t][1]=jy; ji[t][2]=jz; ji[t][3]=nx; ji[t][4]=ny;
    J2[(b*21 + t)*2 + 0] = nx;
    J2[(b*21 + t)*2 + 1] = ny;
  }
  __syncthreads();
  float w1v[5];
  #pragma unroll
  for (int i = 0; i < 5; ++i) w1v[i] = jw1[i*256 + col];
  float b1v = jb1[col];
  #pragma unroll
  for (int jj = 0; jj < 6; ++jj){
    int q = grp + 4*jj;
    if (q < 21){
      float h = b1v;
      #pragma unroll
      for (int i = 0; i < 5; ++i) h += ji[q][i] * w1v[i];
      hid[q][col] = fmaxf(h, 0.f);
    }
  }
  __syncthreads();
  float accq[6];
  float b2v = jb2[col];
  #pragma unroll
  for (int jj = 0; jj < 6; ++jj){
    int q = grp + 4*jj;
    accq[jj] = (q < 21) ? b2v + jid[q*256 + col] : 0.f;
  }
  for (int k = 0; k < 256; k += 4){
    float w0 = jw2[(k+0)*256 + col], w1 = jw2[(k+1)*256 + col];
    float w2 = jw2[(k+2)*256 + col], w3 = jw2[(k+3)*256 + col];
    #pragma unroll
    for (int jj = 0; jj < 6; ++jj){
      int q = grp + 4*jj;
      if (q < 21){
        f32x4 hv = *(const f32x4*)&hid[q][k];
        accq[jj] += hv.x*w0 + hv.y*w1 + hv.z*w2 + hv.w*w3;
      }
    }
  }
  #pragma unroll
  for (int jj = 0; jj < 6; ++jj){
    int q = grp + 4*jj;
    if (q < 21){ jfs[q][col] = accq[jj]; Jf[(size_t)b*5376 + q*256 + col] = accq[jj]; }
  }
  __syncthreads();
  float bqv = bq[col];
  #pragma unroll
  for (int jj = 0; jj < 6; ++jj) accq[jj] = bqv;
  for (int k = 0; k < 256; k += 4){
    float w0 = wq[(k+0)*256 + col], w1 = wq[(k+1)*256 + col];
    float w2 = wq[(k+2)*256 + col], w3 = wq[(k+3)*256 + col];
    #pragma unroll
    for (int jj = 0; jj < 6; ++jj){
      int q = grp + 4*jj;
      if (q < 21){
        f32x4 hv = *(const f32x4*)&jfs[q][k];
        accq[jj] += hv.x*w0 + hv.y*w1 + hv.z*w2 + hv.w*w3;
      }
    }
  }
  #pragma unroll
  for (int jj = 0; jj < 6; ++jj){
    int q = grp + 4*jj;
    if (q < 21) Qw[(size_t)b*5376 + q*256 + col] = accq[jj];
  }
}

// ---------- kernel 4: FUSED LN+K/V GEMM (r9-exact: full-M, BK=64, 20 K-steps, 8 waves) ----------
// Block = (batch, n-quarter): M=512 (K256+V256), N=64. img read/converted exactly once.
__global__ __launch_bounds__(512) void gemm_kv(const unsigned char* __restrict__ Wb,
    const float* __restrict__ img,
    const float* __restrict__ u, const float* __restrict__ v,
    unsigned short* __restrict__ Kt, unsigned short* __restrict__ Vn, int b0){
  __shared__ long As8[4096];           // 32 KB: [kb 8][dd 512] x 8B  (GLL16 dest, linear)
  __shared__ long Bs8[512];            //  4 KB: [kb 8][n 64] x 8B   (swizzled)
  __shared__ float sums_lds[64][8][2]; //  4 KB
  int blk = blockIdx.x;
  int bl = blk >> 2, nblk = blk & 3;
  int bg = b0 + bl;
  int tid = threadIdx.x, lane = tid & 63, wid = tid >> 6;   // 8 waves
  int g = lane >> 4, r = lane & 15;
  int kb_t = wid, n_t = lane;          // staging role: wave = kb row-block, lane = n
  const float* xcol = img + (size_t)bg * 1280 * 256 + nblk*64 + n_t;

  f32x4 acc[4][4];
  #pragma unroll
  for (int i = 0; i < 4; ++i)
    #pragma unroll
    for (int j = 0; j < 4; ++j) acc[i][j] = f32x4{0.f,0.f,0.f,0.f};
  float s = 0.f, s2 = 0.f;

  for (int ks = 0; ks < 20; ++ks){
    // A: async global->LDS, 32 KB = 32 slices of 1 KB, 4 per wave
    #pragma unroll
    for (int i = 0; i < 4; ++i){
      int sl = wid*4 + i;
      int kb = sl >> 2, q = sl & 3;
      const unsigned char* srcA = Wb + ((size_t)((ks*8 + kb) * 512 + q*128 + lane*2)) * 8;
      GLL16(srcA, (char*)As8 + ((kb*512 + q*128 + lane*2) * 8));
    }
    // B: 8 coalesced scalar loads (8-channel column at fixed n), pack -> 1 ds_write_b64
    {
      float t8[8];
      #pragma unroll
      for (int j = 0; j < 8; ++j){
        float val = xcol[(size_t)(ks*64 + kb_t*8 + j) * 256];
        s += val; s2 += val*val;
        t8[j] = val;
      }
      uint2 pk = pack8_fp8(t8);
      int byte = (kb_t*64 + n_t)*8;
      byte ^= ((n_t & 0x30) << 1) ^ ((kb_t & 3) << 3);
      *(uint2*)((char*)Bs8 + byte) = pk;
    }
    __syncthreads();   // drains GLL (vmcnt) + ds_writes (lgkmcnt)
    #pragma unroll
    for (int kk = 0; kk < 2; ++kk){
      long av[4], bv4[4];
      #pragma unroll
      for (int m = 0; m < 4; ++m) av[m] = As8[(kk*4 + g)*512 + wid*64 + m*16 + r];
      #pragma unroll
      for (int nn = 0; nn < 4; ++nn){
        int kb = kk*4 + g;
        int n = nn*16 + r;
        int byt = (kb*64 + n)*8;
        byt ^= ((n & 0x30) << 1) ^ ((kb & 3) << 3);
        bv4[nn] = *(const long*)((char*)Bs8 + byt);
      }
      #pragma unroll
      for (int m = 0; m < 4; ++m)
        #pragma unroll
        for (int nn = 0; nn < 4; ++nn)
          acc[m][nn] = __builtin_amdgcn_mfma_f32_16x16x32_fp8_fp8(av[m], bv4[nn], acc[m][nn], 0, 0, 0);
    }
    __syncthreads();
  }

  // LN stats: thread-local (kb_t, n_t) partials are complete over 160 channels
  sums_lds[n_t][kb_t][0] = s;
  sums_lds[n_t][kb_t][1] = s2;
  __syncthreads();

  int b256l = bl * 256;
  float mean[4], rstd[4];
  #pragma unroll
  for (int nn = 0; nn < 4; ++nn){
    int n_row = nn*16 + r;
    float ss = 0.f, ss2 = 0.f;
    #pragma unroll
    for (int kbi = 0; kbi < 8; ++kbi){ ss += sums_lds[n_row][kbi][0]; ss2 += sums_lds[n_row][kbi][1]; }
    float m = ss * (1.f/1280.f);
    float var = ss2 * (1.f/1280.f) - m * m;
    mean[nn] = m;
    rstd[nn] = rsqrtf(var + 1e-5f);
  }
  #pragma unroll
  for (int m = 0; m < 4; ++m){
    #pragma unroll
    for (int reg = 0; reg < 4; ++reg){
      int dd = wid*64 + m*16 + g*4 + reg;
      float uu = u[dd], vv = v[dd];
      #pragma unroll
      for (int nn = 0; nn < 4; ++nn){
        int n = nblk*64 + nn*16 + r;
        float val = rstd[nn] * (acc[m][nn][reg] * 0.0625f - mean[nn] * uu) + vv;
        unsigned short hbf = f2bf(val);
        if (dd < 256) Kt[(size_t)(b256l + dd) * 256 + n] = hbf;          // K: d-major
        else          Vn[(size_t)(b256l + n) * 256 + (dd - 256)] = hbf;  // V: n-major
      }
    }
  }
}

// ---------- kernel 5: attention (bf16 K/V; XCD-swizzled) ----------
__global__ __launch_bounds__(256) void attnk(const float* __restrict__ Qw, const unsigned short* __restrict__ Kt,
    const unsigned short* __restrict__ Vn, const float* __restrict__ J2, float* __restrict__ AO, int b0){
  __shared__ float Qs[21][64];
  __shared__ float Ls[21][256];
  __shared__ float j2s[21][2];
  int blk = blockIdx.x;
  int xcd = blk & 7, p = blk >> 3;
  int h = p & 3;
  int bl = (p >> 2) * 8 + xcd;
  int bg = b0 + bl;
  int t = threadIdx.x;
  for (int i = t; i < 21*64; i += 256){
    int q = i >> 6, d = i & 63;
    Qs[q][d] = 0.125f * Qw[(size_t)(bg*21 + q) * 256 + h*64 + d];
  }
  if (t < 42) ((float*)j2s)[t] = J2[bg*42 + t];
  __syncthreads();

  int n = t;
  float xn = (float)(n & 15) * 0.125f - 0.9375f;
  float yn = (float)(n >> 4) * 0.125f - 0.9375f;
  float l[21];
  #pragma unroll
  for (int q = 0; q < 21; ++q){
    float dx = j2s[q][0] - xn, dy = j2s[q][1] - yn;
    l[q] = -(dx*dx + dy*dy) * (1.f/0.72f);
  }
  const unsigned short* Kp = Kt + ((size_t)(bl*256) + h*64) * 256 + n;
  for (int d = 0; d < 64; d += 4){
    float k0 = bf2f(Kp[(size_t)(d+0)*256]);
    float k1 = bf2f(Kp[(size_t)(d+1)*256]);
    float k2 = bf2f(Kp[(size_t)(d+2)*256]);
    float k3 = bf2f(Kp[(size_t)(d+3)*256]);
    #pragma unroll
    for (int q = 0; q < 21; ++q){
      f32x4 qv = *(const f32x4*)&Qs[q][d];
      l[q] += qv.x*k0 + qv.y*k1 + qv.z*k2 + qv.w*k3;
    }
  }
  #pragma unroll
  for (int q = 0; q < 21; ++q) Ls[q][n] = l[q];
  __syncthreads();

  int wv_ = t >> 6, lane = t & 63;
  for (int q = wv_; q < 21; q += 4){
    float v0 = Ls[q][lane], v1 = Ls[q][lane+64], v2 = Ls[q][lane+128], v3 = Ls[q][lane+192];
    float mx = fmaxf(fmaxf(v0, v1), fmaxf(v2, v3));
    #pragma unroll
    for (int off = 32; off >= 1; off >>= 1) mx = fmaxf(mx, __shfl_xor(mx, off));
    float e0 = __expf(v0 - mx), e1 = __expf(v1 - mx), e2 = __expf(v2 - mx), e3 = __expf(v3 - mx);
    float ss = e0 + e1 + e2 + e3;
    #pragma unroll
    for (int off = 32; off >= 1; off >>= 1) ss += __shfl_xor(ss, off);
    float inv = 1.f / ss;
    Ls[q][lane] = e0*inv; Ls[q][lane+64] = e1*inv; Ls[q][lane+128] = e2*inv; Ls[q][lane+192] = e3*inv;
  }
  __syncthreads();

  int d = t & 63, grp = t >> 6;
  const unsigned short* Vp = Vn + (size_t)(bl*256) * 256 + h*64 + d;
  float aq[6] = {0.f,0.f,0.f,0.f,0.f,0.f};
  for (int n2b = 0; n2b < 256; n2b += 32){
    float vdec[32];
    #pragma unroll
    for (int i = 0; i < 32; ++i) vdec[i] = bf2f(Vp[(size_t)(n2b + i) * 256]);
    #pragma unroll
    for (int j = 0; j < 6; ++j){
      int q = grp + 4*j;
      if (q < 21){
        float sacc = 0.f;
        #pragma unroll
        for (int i = 0; i < 32; ++i) sacc += Ls[q][n2b + i] * vdec[i];
        aq[j] += sacc;
      }
    }
  }
  #pragma unroll
  for (int j = 0; j < 6; ++j){
    int q = grp + 4*j;
    if (q < 21) AO[(size_t)(bg*21 + q) * 256 + h*64 + d] = aq[j];
  }
}

// ---------- kernel 6: out-proj + LN + decoder heads (1024 threads) ----------
__global__ __launch_bounds__(1024) void headk(const float* __restrict__ AO, const float* __restrict__ Jf,
    const float* __restrict__ wo, const float* __restrict__ bo,
    const float* __restrict__ ng, const float* __restrict__ nb_,
    const float* __restrict__ dpw, const float* __restrict__ dpb,
    const float* __restrict__ dsw, const float* __restrict__ dsb,
    const float* __restrict__ dcw, const float* __restrict__ dcb,
    const float* __restrict__ pls, const float* __restrict__ bls, const float* __restrict__ cls,
    const float* __restrict__ prot, const float* __restrict__ betas, const float* __restrict__ cam,
    float* __restrict__ out){
  __shared__ float AOs[21][256];
  __shared__ float Os[21][256];
  __shared__ float mst[21], rst[21];
  __shared__ float pp[21][48];
  __shared__ float dp[48];
  __shared__ float mb[256];
  int b = blockIdx.x, t = threadIdx.x;
  int col = t & 255, grp = t >> 8;
  for (int i = t; i < 5376; i += 1024) ((float*)AOs)[i] = AO[(size_t)b*5376 + i];
  __syncthreads();

  float accq[6];
  float bov = bo[col];
  #pragma unroll
  for (int jj = 0; jj < 6; ++jj){
    int q = grp + 4*jj;
    accq[jj] = (q < 21) ? bov + Jf[(size_t)b*5376 + q*256 + col] : 0.f;
  }
  for (int k = 0; k < 256; k += 4){
    float w0 = wo[(k+0)*256 + col], w1 = wo[(k+1)*256 + col];
    float w2 = wo[(k+2)*256 + col], w3 = wo[(k+3)*256 + col];
    #pragma unroll
    for (int jj = 0; jj < 6; ++jj){
      int q = grp + 4*jj;
      if (q < 21){
        f32x4 av = *(const f32x4*)&AOs[q][k];
        accq[jj] += av.x*w0 + av.y*w1 + av.z*w2 + av.w*w3;
      }
    }
  }
  #pragma unroll
  for (int jj = 0; jj < 6; ++jj){
    int q = grp + 4*jj;
    if (q < 21) Os[q][col] = accq[jj];
  }
  __syncthreads();

  int w = t >> 6, lane = t & 63;
  for (int q = w; q < 21; q += 16){
    float v0 = Os[q][lane], v1 = Os[q][lane+64], v2 = Os[q][lane+128], v3 = Os[q][lane+192];
    float s = v0+v1+v2+v3;
    float s2 = v0*v0+v1*v1+v2*v2+v3*v3;
    #pragma unroll
    for (int off = 32; off >= 1; off >>= 1){ s += __shfl_xor(s, off); s2 += __shfl_xor(s2, off); }
    if (lane == 0){
      float m = s * (1.f/256.f);
      float var = s2 * (1.f/256.f) - m*m;
      mst[q] = m; rst[q] = rsqrtf(var + 1e-5f);
    }
  }
  __syncthreads();

  float gg = ng[col], bb = nb_[col];
  #pragma unroll
  for (int jj = 0; jj < 6; ++jj){
    int q = grp + 4*jj;
    if (q < 21) Os[q][col] = (accq[jj] - mst[q]) * rst[q] * gg + bb;
  }
  __syncthreads();

  if (t < 256){
    float s = 0.f;
    #pragma unroll
    for (int q = 0; q < 21; ++q) s += Os[q][t];
    mb[t] = s * (1.f/21.f);
  }
  if (t < 1008){
    int q = t / 48, j = t % 48;
    float a = 0.f;
    for (int k = 0; k < 256; k += 4){
      f32x4 ov = *(const f32x4*)&Os[q][k];
      const float* wp = dpw + (size_t)(q*256 + k) * 48 + j;
      a += ov.x*wp[0] + ov.y*wp[48] + ov.z*wp[96] + ov.w*wp[144];
    }
    pp[q][j] = a;
  }
  __syncthreads();

  float e_p = __expf(pls[0]), e_b = __expf(bls[0]), e_c = __expf(cls[0]);
  if (t < 48){
    float a = dpb[t];
    #pragma unroll
    for (int q = 0; q < 21; ++q) a += pp[q][t];
    dp[t] = a * e_p;
  }
  __syncthreads();

  if (t < 16){
    int j = t;
    float ax = dp[3*j], ay = dp[3*j+1], az = dp[3*j+2];
    float ang = sqrtf(ax*ax + ay*ay + az*az + 1e-16f);
    float inv = 1.f / ang;
    float x = ax*inv, y = ay*inv, z = az*inv;
    float s_ = sinf(ang), c_ = cosf(ang), mc = 1.f - c_;
    float R00 = 1.f - mc*(y*y + z*z), R01 = -s_*z + mc*x*y,      R02 = s_*y + mc*x*z;
    float R10 = s_*z + mc*x*y,        R11 = 1.f - mc*(x*x + z*z), R12 = -s_*x + mc*y*z;
    float R20 = -s_*y + mc*x*z,       R21 = s_*x + mc*y*z,        R22 = 1.f - mc*(x*x + y*y);
    const float* P = prot + (size_t)(b*16 + j) * 9;
    float p0=P[0],p1=P[1],p2=P[2],p3=P[3],p4=P[4],p5=P[5],p6=P[6],p7=P[7],p8=P[8];
    float* o = out + (size_t)(b*16 + j) * 9;
    o[0]=R00*p0 + R01*p3 + R02*p6; o[1]=R00*p1 + R01*p4 + R02*p7; o[2]=R00*p2 + R01*p5 + R02*p8;
    o[3]=R10*p0 + R11*p3 + R12*p6; o[4]=R10*p1 + R11*p4 + R12*p7; o[5]=R10*p2 + R11*p5 + R12*p8;
    o[6]=R20*p0 + R21*p3 + R22*p6; o[7]=R20*p1 + R21*p4 + R22*p7; o[8]=R20*p2 + R21*p5 + R22*p8;
  }
  if (w >= 4 && w < 14){
    int j = w - 4;
    float a = 0.f;
    #pragma unroll
    for (int i = 0; i < 4; ++i){
      int k = lane + 64*i;
      a += mb[k] * dsw[k*10 + j];
    }
    #pragma unroll
    for (int off = 32; off >= 1; off >>= 1) a += __shfl_xor(a, off);
    if (lane == 0) out[18432 + b*10 + j] = betas[b*10 + j] + (a + dsb[j]) * e_b;
  }
  if (w >= 1 && w < 4){
    int j = w - 1;
    float a = 0.f;
    #pragma unroll
    for (int i = 0; i < 4; ++i){
      int k = lane + 64*i;
      a += Os[0][k] * dcw[k*3 + j];
    }
    #pragma unroll
    for (int off = 32; off >= 1; off >>= 1) a += __shfl_xor(a, off);
    if (lane == 0) out[19712 + b*3 + j] = cam[b*3 + j] + (a + dcb[j]) * e_c;
  }
}

// ---------- launch ----------
extern "C" void kernel_launch(void* const* d_in, const int* in_sizes, int n_in,
                              void* d_out, int out_size, void* d_ws, size_t ws_size,
                              hipStream_t stream) {
  const float* img    = (const float*)d_in[0];
  const float* joints = (const float*)d_in[1];
  const float* pcam   = (const float*)d_in[2];
  const float* focal  = (const float*)d_in[3];
  const float* prot   = (const float*)d_in[4];
  const float* betas  = (const float*)d_in[5];
  const float* cam    = (const float*)d_in[6];
  const float* ln_g   = (const float*)d_in[7];
  const float* ln_b   = (const float*)d_in[8];
  const float* wk     = (const float*)d_in[9];
  const float* bk     = (const float*)d_in[10];
  const float* wv     = (const float*)d_in[11];
  const float* bv     = (const float*)d_in[12];
  const float* jw1    = (const float*)d_in[13];
  const float* jb1    = (const float*)d_in[14];
  const float* jw2    = (const float*)d_in[15];
  const float* jb2    = (const float*)d_in[16];
  const float* jid    = (const float*)d_in[17];
  const float* wq     = (const float*)d_in[18];
  const float* bq     = (const float*)d_in[19];
  const float* wo     = (const float*)d_in[20];
  const float* bo     = (const float*)d_in[21];
  const float* ng     = (const float*)d_in[22];
  const float* nb     = (const float*)d_in[23];
  const float* dpw    = (const float*)d_in[24];
  const float* dpb    = (const float*)d_in[25];
  const float* dsw    = (const float*)d_in[26];
  const float* dsb    = (const float*)d_in[27];
  const float* dcw    = (const float*)d_in[28];
  const float* dcb    = (const float*)d_in[29];
  const float* pls    = (const float*)d_in[30];
  const float* bls    = (const float*)d_in[31];
  const float* cls    = (const float*)d_in[32];

  // Fixed region (9,004,032 B), then batch-chunked Kt/Vn (bf16).
  char* ws = (char*)d_ws;
  float*         uvP = (float*)(ws + 0);                 //    65,536
  float*         u   = (float*)(ws + 65536);             //     2,048
  float*         v   = (float*)(ws + 67584);             //     2,048
  unsigned char* Wb  = (unsigned char*)(ws + 69632);     //   655,360
  float*         Jf  = (float*)(ws + 724992);            // 2,752,512
  float*         Qw  = (float*)(ws + 3477504);           // 2,752,512
  float*         J2  = (float*)(ws + 6230016);           //    21,504
  float*         AO  = (float*)(ws + 6251520);           // 2,752,512
  const size_t FIXED = 9004032;

  // chunked: Kt 16,777,216 + Vn 16,777,216 (bf16, full batch)
  int NC = 16;
  for (int c = 1; c <= 16; c <<= 1){
    size_t need = FIXED + (size_t)33554432 / c;
    if (need <= ws_size){ NC = c; break; }
  }
  int Bc = 128 / NC;
  size_t kv_bytes = (size_t)16777216 / NC;
  unsigned short* Kt = (unsigned short*)(ws + FIXED);
  unsigned short* Vn = (unsigned short*)(ws + FIXED + kv_bytes);

  float* out = (float*)d_out;  // f32 outputs

  prep_w <<<16,  512, 0, stream>>>(wk, wv, ln_g, ln_b, Wb, uvP);
  jointk <<<128, 1024, 0, stream>>>(joints, pcam, focal, jw1, jb1, jw2, jb2, jid, wq, bq,
                                    uvP, bk, bv, u, v, Jf, Qw, J2);
  for (int c = 0; c < NC; ++c){
    int b0 = c * Bc;
    gemm_kv <<<Bc*4, 512, 0, stream>>>(Wb, img, u, v, Kt, Vn, b0);
    attnk   <<<Bc*4, 256, 0, stream>>>(Qw, Kt, Vn, J2, AO, b0);
  }
  headk  <<<128, 1024, 0, stream>>>(AO, Jf, wo, bo, ng, nb, dpw, dpb, dsw, dsb, dcw, dcb, pls, bls, cls, prot, betas, cam, out);
}

// Round 18
// 159.305 us; speedup vs baseline: 1.5217x; 1.0748x over previous
//
#include <hip/hip_runtime.h>
#include <cstdint>
#include <cstddef>

// ---------- types ----------
typedef __attribute__((ext_vector_type(4))) float f32x4;

typedef const __attribute__((address_space(1))) void gv_t;
typedef __attribute__((address_space(3))) void lv_t;
#define GLL16(gsrc, ldst) __builtin_amdgcn_global_load_lds((gv_t*)(gsrc), (lv_t*)(ldst), 16, 0, 0)

// fp8 e4m3 (OCP) helpers — op_sel must be a literal constant -> template param
template<bool HI>
__device__ __forceinline__ unsigned pk_fp8(float a, float b, unsigned old){
  return (unsigned)__builtin_amdgcn_cvt_pk_fp8_f32(a, b, (int)old, HI);
}
__device__ __forceinline__ uint2 pack8_fp8(const float* v){
  unsigned lo = pk_fp8<false>(v[0], v[1], 0u);
  lo = pk_fp8<true>(v[2], v[3], lo);
  unsigned hi = pk_fp8<false>(v[4], v[5], 0u);
  hi = pk_fp8<true>(v[6], v[7], hi);
  return make_uint2(lo, hi);
}
__device__ __forceinline__ unsigned short f2bf(float f){
  unsigned u = __builtin_bit_cast(unsigned, f);
  u += 0x7fffu + ((u >> 16) & 1u);
  return (unsigned short)(u >> 16);
}
__device__ __forceinline__ float bf2f(unsigned short h){
  unsigned u = ((unsigned)h) << 16;
  return __builtin_bit_cast(float, u);
}

// Problem constants: B=128, C=1280, N=256 tokens, BD=256, NH=4, HD=64, NQ=21, NJ=16
// W scale: Wb stores fp8(16*g*w); img staged as fp8(x); gemm acc scaled by 1/16.

// ---------- kernel 1: W prep (plain layout) ----------
__global__ __launch_bounds__(512) void prep_w(const float* __restrict__ wk, const float* __restrict__ wv,
                                              const float* __restrict__ g, const float* __restrict__ bl,
                                              unsigned char* __restrict__ Wb, float* __restrict__ uvP){
  int dd = threadIdx.x;           // 0..511  (0..255 -> K, 256..511 -> V)
  int cs = blockIdx.x;            // 16 chunks of 80 channels
  const float* w = (dd < 256) ? (wk + dd) : (wv + (dd - 256));
  float uu = 0.f, vv = 0.f;
  for (int cb = 0; cb < 80; cb += 8){
    int c0 = cs * 80 + cb;
    float tmp[8];
    #pragma unroll
    for (int i = 0; i < 8; ++i){
      int c = c0 + i;
      float wc = w[(size_t)c * 256];
      float gw = g[c] * wc;
      uu += gw;
      vv += bl[c] * wc;
      tmp[i] = 16.f * gw;
    }
    uint2 pk = pack8_fp8(tmp);
    *(uint2*)(Wb + ((size_t)(c0 >> 3) * 512 + dd) * 8) = pk;
  }
  uvP[(cs * 2 + 0) * 512 + dd] = uu;
  uvP[(cs * 2 + 1) * 512 + dd] = vv;
}

// ---------- kernel 3: joint embed + Q projection (1024 threads) + folded reduce_uv ----------
__global__ __launch_bounds__(1024) void jointk(const float* __restrict__ joints, const float* __restrict__ pcam,
    const float* __restrict__ focal,
    const float* __restrict__ jw1, const float* __restrict__ jb1,
    const float* __restrict__ jw2, const float* __restrict__ jb2,
    const float* __restrict__ jid, const float* __restrict__ wq, const float* __restrict__ bq,
    const float* __restrict__ uvP, const float* __restrict__ bk, const float* __restrict__ bv,
    float* __restrict__ u, float* __restrict__ v,
    float* __restrict__ Jf, float* __restrict__ Qw, float* __restrict__ J2){
  __shared__ float ji[21][5];
  __shared__ float hid[21][256];
  __shared__ float jfs[21][256];
  int b = blockIdx.x, t = threadIdx.x;
  int col = t & 255, grp = t >> 8;
  // folded reduce_uv: block 0 threads 0..511 write u,v (consumed by gemm, launched later)
  if (b == 0 && t < 512){
    float su = 0.f, sv = 0.f;
    #pragma unroll
    for (int cs = 0; cs < 16; ++cs){
      su += uvP[(cs * 2 + 0) * 512 + t];
      sv += uvP[(cs * 2 + 1) * 512 + t];
    }
    u[t] = su;
    v[t] = sv + ((t < 256) ? bk[t] : bv[t - 256]);
  }
  if (t < 21){
    float sc = pcam[b*3], tx = pcam[b*3+1], ty = pcam[b*3+2];
    float f0 = focal[b*2], f1 = focal[b*2+1];
    float tz = 2.f * f0 / (256.f * sc + 1e-9f);
    const float* jp = joints + (size_t)(b*21 + t) * 3;
    float jx = jp[0], jy = jp[1], jz = jp[2];
    float cx = jx + tx, cy = jy + ty, cz = jz + tz;
    float zz = fmaxf(cz, 1e-6f);
    float nx = (cx / zz) * f0 * (1.f/128.f);
    float ny = (cy / zz) * f1 * (1.f/128.f);
    ji[t][0]=jx; ji[t][1]=jy; ji[t][2]=jz; ji[t][3]=nx; ji[t][4]=ny;
    J2[(b*21 + t)*2 + 0] = nx;
    J2[(b*21 + t)*2 + 1] = ny;
  }
  __syncthreads();
  float w1v[5];
  #pragma unroll
  for (int i = 0; i < 5; ++i) w1v[i] = jw1[i*256 + col];
  float b1v = jb1[col];
  #pragma unroll
  for (int jj = 0; jj < 6; ++jj){
    int q = grp + 4*jj;
    if (q < 21){
      float h = b1v;
      #pragma unroll
      for (int i = 0; i < 5; ++i) h += ji[q][i] * w1v[i];
      hid[q][col] = fmaxf(h, 0.f);
    }
  }
  __syncthreads();
  float accq[6];
  float b2v = jb2[col];
  #pragma unroll
  for (int jj = 0; jj < 6; ++jj){
    int q = grp + 4*jj;
    accq[jj] = (q < 21) ? b2v + jid[q*256 + col] : 0.f;
  }
  for (int k = 0; k < 256; k += 4){
    float w0 = jw2[(k+0)*256 + col], w1 = jw2[(k+1)*256 + col];
    float w2 = jw2[(k+2)*256 + col], w3 = jw2[(k+3)*256 + col];
    #pragma unroll
    for (int jj = 0; jj < 6; ++jj){
      int q = grp + 4*jj;
      if (q < 21){
        f32x4 hv = *(const f32x4*)&hid[q][k];
        accq[jj] += hv.x*w0 + hv.y*w1 + hv.z*w2 + hv.w*w3;
      }
    }
  }
  #pragma unroll
  for (int jj = 0; jj < 6; ++jj){
    int q = grp + 4*jj;
    if (q < 21){ jfs[q][col] = accq[jj]; Jf[(size_t)b*5376 + q*256 + col] = accq[jj]; }
  }
  __syncthreads();
  float bqv = bq[col];
  #pragma unroll
  for (int jj = 0; jj < 6; ++jj) accq[jj] = bqv;
  for (int k = 0; k < 256; k += 4){
    float w0 = wq[(k+0)*256 + col], w1 = wq[(k+1)*256 + col];
    float w2 = wq[(k+2)*256 + col], w3 = wq[(k+3)*256 + col];
    #pragma unroll
    for (int jj = 0; jj < 6; ++jj){
      int q = grp + 4*jj;
      if (q < 21){
        f32x4 hv = *(const f32x4*)&jfs[q][k];
        accq[jj] += hv.x*w0 + hv.y*w1 + hv.z*w2 + hv.w*w3;
      }
    }
  }
  #pragma unroll
  for (int jj = 0; jj < 6; ++jj){
    int q = grp + 4*jj;
    if (q < 21) Qw[(size_t)b*5376 + q*256 + col] = accq[jj];
  }
}

// ---------- kernel 4: FUSED LN+K/V GEMM (r9-exact structure; V now stored d-major) ----------
// Block = (batch, n-quarter): M=512 (K256+V256), N=64, BK=64, 20 K-steps, 8 waves.
__global__ __launch_bounds__(512) void gemm_kv(const unsigned char* __restrict__ Wb,
    const float* __restrict__ img,
    const float* __restrict__ u, const float* __restrict__ v,
    unsigned short* __restrict__ Kt, unsigned short* __restrict__ Vt, int b0){
  __shared__ long As8[4096];           // 32 KB: [kb 8][dd 512] x 8B  (GLL16 dest, linear)
  __shared__ long Bs8[512];            //  4 KB: [kb 8][n 64] x 8B   (swizzled)
  __shared__ float sums_lds[64][8][2]; //  4 KB
  int blk = blockIdx.x;
  int bl = blk >> 2, nblk = blk & 3;
  int bg = b0 + bl;
  int tid = threadIdx.x, lane = tid & 63, wid = tid >> 6;   // 8 waves
  int g = lane >> 4, r = lane & 15;
  int kb_t = wid, n_t = lane;          // staging role: wave = kb row-block, lane = n
  const float* xcol = img + (size_t)bg * 1280 * 256 + nblk*64 + n_t;

  f32x4 acc[4][4];
  #pragma unroll
  for (int i = 0; i < 4; ++i)
    #pragma unroll
    for (int j = 0; j < 4; ++j) acc[i][j] = f32x4{0.f,0.f,0.f,0.f};
  float s = 0.f, s2 = 0.f;

  for (int ks = 0; ks < 20; ++ks){
    // A: async global->LDS, 32 KB = 32 slices of 1 KB, 4 per wave
    #pragma unroll
    for (int i = 0; i < 4; ++i){
      int sl = wid*4 + i;
      int kb = sl >> 2, q = sl & 3;
      const unsigned char* srcA = Wb + ((size_t)((ks*8 + kb) * 512 + q*128 + lane*2)) * 8;
      GLL16(srcA, (char*)As8 + ((kb*512 + q*128 + lane*2) * 8));
    }
    // B: 8 coalesced scalar loads (8-channel column at fixed n), pack -> 1 ds_write_b64
    {
      float t8[8];
      #pragma unroll
      for (int j = 0; j < 8; ++j){
        float val = xcol[(size_t)(ks*64 + kb_t*8 + j) * 256];
        s += val; s2 += val*val;
        t8[j] = val;
      }
      uint2 pk = pack8_fp8(t8);
      int byte = (kb_t*64 + n_t)*8;
      byte ^= ((n_t & 0x30) << 1) ^ ((kb_t & 3) << 3);
      *(uint2*)((char*)Bs8 + byte) = pk;
    }
    __syncthreads();   // drains GLL (vmcnt) + ds_writes (lgkmcnt)
    #pragma unroll
    for (int kk = 0; kk < 2; ++kk){
      long av[4], bv4[4];
      #pragma unroll
      for (int m = 0; m < 4; ++m) av[m] = As8[(kk*4 + g)*512 + wid*64 + m*16 + r];
      #pragma unroll
      for (int nn = 0; nn < 4; ++nn){
        int kb = kk*4 + g;
        int n = nn*16 + r;
        int byt = (kb*64 + n)*8;
        byt ^= ((n & 0x30) << 1) ^ ((kb & 3) << 3);
        bv4[nn] = *(const long*)((char*)Bs8 + byt);
      }
      #pragma unroll
      for (int m = 0; m < 4; ++m)
        #pragma unroll
        for (int nn = 0; nn < 4; ++nn)
          acc[m][nn] = __builtin_amdgcn_mfma_f32_16x16x32_fp8_fp8(av[m], bv4[nn], acc[m][nn], 0, 0, 0);
    }
    __syncthreads();
  }

  // LN stats: thread-local (kb_t, n_t) partials are complete over 160 channels
  sums_lds[n_t][kb_t][0] = s;
  sums_lds[n_t][kb_t][1] = s2;
  __syncthreads();

  int b256l = bl * 256;
  float mean[4], rstd[4];
  #pragma unroll
  for (int nn = 0; nn < 4; ++nn){
    int n_row = nn*16 + r;
    float ss = 0.f, ss2 = 0.f;
    #pragma unroll
    for (int kbi = 0; kbi < 8; ++kbi){ ss += sums_lds[n_row][kbi][0]; ss2 += sums_lds[n_row][kbi][1]; }
    float m = ss * (1.f/1280.f);
    float var = ss2 * (1.f/1280.f) - m * m;
    mean[nn] = m;
    rstd[nn] = rsqrtf(var + 1e-5f);
  }
  #pragma unroll
  for (int m = 0; m < 4; ++m){
    #pragma unroll
    for (int reg = 0; reg < 4; ++reg){
      int dd = wid*64 + m*16 + g*4 + reg;
      float uu = u[dd], vv = v[dd];
      #pragma unroll
      for (int nn = 0; nn < 4; ++nn){
        int n = nblk*64 + nn*16 + r;
        float val = rstd[nn] * (acc[m][nn][reg] * 0.0625f - mean[nn] * uu) + vv;
        unsigned short hbf = f2bf(val);
        if (dd < 256) Kt[(size_t)(b256l + dd) * 256 + n] = hbf;            // K: d-major
        else          Vt[(size_t)(b256l + (dd - 256)) * 256 + n] = hbf;    // V: d-major too
      }
    }
  }
}

// ---------- kernel 5: attention (bf16 K/V; V read per-lane contiguous, vectorized) ----------
__global__ __launch_bounds__(256) void attnk(const float* __restrict__ Qw, const unsigned short* __restrict__ Kt,
    const unsigned short* __restrict__ Vt, const float* __restrict__ J2, float* __restrict__ AO, int b0){
  __shared__ float Qs[21][64];
  __shared__ float Ls[21][256];
  __shared__ float j2s[21][2];
  int blk = blockIdx.x;
  int xcd = blk & 7, p = blk >> 3;
  int h = p & 3;
  int bl = (p >> 2) * 8 + xcd;
  int bg = b0 + bl;
  int t = threadIdx.x;
  for (int i = t; i < 21*64; i += 256){
    int q = i >> 6, d = i & 63;
    Qs[q][d] = 0.125f * Qw[(size_t)(bg*21 + q) * 256 + h*64 + d];
  }
  if (t < 42) ((float*)j2s)[t] = J2[bg*42 + t];
  __syncthreads();

  int n = t;
  float xn = (float)(n & 15) * 0.125f - 0.9375f;
  float yn = (float)(n >> 4) * 0.125f - 0.9375f;
  float l[21];
  #pragma unroll
  for (int q = 0; q < 21; ++q){
    float dx = j2s[q][0] - xn, dy = j2s[q][1] - yn;
    l[q] = -(dx*dx + dy*dy) * (1.f/0.72f);
  }
  const unsigned short* Kp = Kt + ((size_t)(bl*256) + h*64) * 256 + n;
  for (int d = 0; d < 64; d += 4){
    float k0 = bf2f(Kp[(size_t)(d+0)*256]);
    float k1 = bf2f(Kp[(size_t)(d+1)*256]);
    float k2 = bf2f(Kp[(size_t)(d+2)*256]);
    float k3 = bf2f(Kp[(size_t)(d+3)*256]);
    #pragma unroll
    for (int q = 0; q < 21; ++q){
      f32x4 qv = *(const f32x4*)&Qs[q][d];
      l[q] += qv.x*k0 + qv.y*k1 + qv.z*k2 + qv.w*k3;
    }
  }
  #pragma unroll
  for (int q = 0; q < 21; ++q) Ls[q][n] = l[q];
  __syncthreads();

  int wv_ = t >> 6, lane = t & 63;
  for (int q = wv_; q < 21; q += 4){
    float v0 = Ls[q][lane], v1 = Ls[q][lane+64], v2 = Ls[q][lane+128], v3 = Ls[q][lane+192];
    float mx = fmaxf(fmaxf(v0, v1), fmaxf(v2, v3));
    #pragma unroll
    for (int off = 32; off >= 1; off >>= 1) mx = fmaxf(mx, __shfl_xor(mx, off));
    float e0 = __expf(v0 - mx), e1 = __expf(v1 - mx), e2 = __expf(v2 - mx), e3 = __expf(v3 - mx);
    float ss = e0 + e1 + e2 + e3;
    #pragma unroll
    for (int off = 32; off >= 1; off >>= 1) ss += __shfl_xor(ss, off);
    float inv = 1.f / ss;
    Ls[q][lane] = e0*inv; Ls[q][lane+64] = e1*inv; Ls[q][lane+128] = e2*inv; Ls[q][lane+192] = e3*inv;
  }
  __syncthreads();

  // PV: V is d-major; thread (d,grp) streams its own 512B row contiguously (uint4 = 8 bf16)
  int d = t & 63, grp = t >> 6;
  const unsigned short* Vp = Vt + ((size_t)(bl*256) + h*64 + d) * 256;
  float aq[6] = {0.f,0.f,0.f,0.f,0.f,0.f};
  for (int n2b = 0; n2b < 256; n2b += 32){
    float vdec[32];
    #pragma unroll
    for (int c8 = 0; c8 < 4; ++c8){
      uint4 pk = *(const uint4*)(Vp + n2b + c8*8);
      vdec[c8*8+0] = bf2f((unsigned short)(pk.x & 0xffffu));
      vdec[c8*8+1] = bf2f((unsigned short)(pk.x >> 16));
      vdec[c8*8+2] = bf2f((unsigned short)(pk.y & 0xffffu));
      vdec[c8*8+3] = bf2f((unsigned short)(pk.y >> 16));
      vdec[c8*8+4] = bf2f((unsigned short)(pk.z & 0xffffu));
      vdec[c8*8+5] = bf2f((unsigned short)(pk.z >> 16));
      vdec[c8*8+6] = bf2f((unsigned short)(pk.w & 0xffffu));
      vdec[c8*8+7] = bf2f((unsigned short)(pk.w >> 16));
    }
    #pragma unroll
    for (int j = 0; j < 6; ++j){
      int q = grp + 4*j;
      if (q < 21){
        float sacc = 0.f;
        #pragma unroll
        for (int i = 0; i < 32; ++i) sacc += Ls[q][n2b + i] * vdec[i];
        aq[j] += sacc;
      }
    }
  }
  #pragma unroll
  for (int j = 0; j < 6; ++j){
    int q = grp + 4*j;
    if (q < 21) AO[(size_t)(bg*21 + q) * 256 + h*64 + d] = aq[j];
  }
}

// ---------- kernel 6: out-proj + LN + decoder heads (1024 threads) ----------
__global__ __launch_bounds__(1024) void headk(const float* __restrict__ AO, const float* __restrict__ Jf,
    const float* __restrict__ wo, const float* __restrict__ bo,
    const float* __restrict__ ng, const float* __restrict__ nb_,
    const float* __restrict__ dpw, const float* __restrict__ dpb,
    const float* __restrict__ dsw, const float* __restrict__ dsb,
    const float* __restrict__ dcw, const float* __restrict__ dcb,
    const float* __restrict__ pls, const float* __restrict__ bls, const float* __restrict__ cls,
    const float* __restrict__ prot, const float* __restrict__ betas, const float* __restrict__ cam,
    float* __restrict__ out){
  __shared__ float AOs[21][256];
  __shared__ float Os[21][256];
  __shared__ float mst[21], rst[21];
  __shared__ float pp[21][48];
  __shared__ float dp[48];
  __shared__ float mb[256];
  int b = blockIdx.x, t = threadIdx.x;
  int col = t & 255, grp = t >> 8;
  for (int i = t; i < 5376; i += 1024) ((float*)AOs)[i] = AO[(size_t)b*5376 + i];
  __syncthreads();

  float accq[6];
  float bov = bo[col];
  #pragma unroll
  for (int jj = 0; jj < 6; ++jj){
    int q = grp + 4*jj;
    accq[jj] = (q < 21) ? bov + Jf[(size_t)b*5376 + q*256 + col] : 0.f;
  }
  for (int k = 0; k < 256; k += 4){
    float w0 = wo[(k+0)*256 + col], w1 = wo[(k+1)*256 + col];
    float w2 = wo[(k+2)*256 + col], w3 = wo[(k+3)*256 + col];
    #pragma unroll
    for (int jj = 0; jj < 6; ++jj){
      int q = grp + 4*jj;
      if (q < 21){
        f32x4 av = *(const f32x4*)&AOs[q][k];
        accq[jj] += av.x*w0 + av.y*w1 + av.z*w2 + av.w*w3;
      }
    }
  }
  #pragma unroll
  for (int jj = 0; jj < 6; ++jj){
    int q = grp + 4*jj;
    if (q < 21) Os[q][col] = accq[jj];
  }
  __syncthreads();

  int w = t >> 6, lane = t & 63;
  for (int q = w; q < 21; q += 16){
    float v0 = Os[q][lane], v1 = Os[q][lane+64], v2 = Os[q][lane+128], v3 = Os[q][lane+192];
    float s = v0+v1+v2+v3;
    float s2 = v0*v0+v1*v1+v2*v2+v3*v3;
    #pragma unroll
    for (int off = 32; off >= 1; off >>= 1){ s += __shfl_xor(s, off); s2 += __shfl_xor(s2, off); }
    if (lane == 0){
      float m = s * (1.f/256.f);
      float var = s2 * (1.f/256.f) - m*m;
      mst[q] = m; rst[q] = rsqrtf(var + 1e-5f);
    }
  }
  __syncthreads();

  float gg = ng[col], bb = nb_[col];
  #pragma unroll
  for (int jj = 0; jj < 6; ++jj){
    int q = grp + 4*jj;
    if (q < 21) Os[q][col] = (accq[jj] - mst[q]) * rst[q] * gg + bb;
  }
  __syncthreads();

  if (t < 256){
    float s = 0.f;
    #pragma unroll
    for (int q = 0; q < 21; ++q) s += Os[q][t];
    mb[t] = s * (1.f/21.f);
  }
  if (t < 1008){
    int q = t / 48, j = t % 48;
    float a = 0.f;
    for (int k = 0; k < 256; k += 4){
      f32x4 ov = *(const f32x4*)&Os[q][k];
      const float* wp = dpw + (size_t)(q*256 + k) * 48 + j;
      a += ov.x*wp[0] + ov.y*wp[48] + ov.z*wp[96] + ov.w*wp[144];
    }
    pp[q][j] = a;
  }
  __syncthreads();

  float e_p = __expf(pls[0]), e_b = __expf(bls[0]), e_c = __expf(cls[0]);
  if (t < 48){
    float a = dpb[t];
    #pragma unroll
    for (int q = 0; q < 21; ++q) a += pp[q][t];
    dp[t] = a * e_p;
  }
  __syncthreads();

  if (t < 16){
    int j = t;
    float ax = dp[3*j], ay = dp[3*j+1], az = dp[3*j+2];
    float ang = sqrtf(ax*ax + ay*ay + az*az + 1e-16f);
    float inv = 1.f / ang;
    float x = ax*inv, y = ay*inv, z = az*inv;
    float s_ = sinf(ang), c_ = cosf(ang), mc = 1.f - c_;
    float R00 = 1.f - mc*(y*y + z*z), R01 = -s_*z + mc*x*y,      R02 = s_*y + mc*x*z;
    float R10 = s_*z + mc*x*y,        R11 = 1.f - mc*(x*x + z*z), R12 = -s_*x + mc*y*z;
    float R20 = -s_*y + mc*x*z,       R21 = s_*x + mc*y*z,        R22 = 1.f - mc*(x*x + y*y);
    const float* P = prot + (size_t)(b*16 + j) * 9;
    float p0=P[0],p1=P[1],p2=P[2],p3=P[3],p4=P[4],p5=P[5],p6=P[6],p7=P[7],p8=P[8];
    float* o = out + (size_t)(b*16 + j) * 9;
    o[0]=R00*p0 + R01*p3 + R02*p6; o[1]=R00*p1 + R01*p4 + R02*p7; o[2]=R00*p2 + R01*p5 + R02*p8;
    o[3]=R10*p0 + R11*p3 + R12*p6; o[4]=R10*p1 + R11*p4 + R12*p7; o[5]=R10*p2 + R11*p5 + R12*p8;
    o[6]=R20*p0 + R21*p3 + R22*p6; o[7]=R20*p1 + R21*p4 + R22*p7; o[8]=R20*p2 + R21*p5 + R22*p8;
  }
  if (w >= 4 && w < 14){
    int j = w - 4;
    float a = 0.f;
    #pragma unroll
    for (int i = 0; i < 4; ++i){
      int k = lane + 64*i;
      a += mb[k] * dsw[k*10 + j];
    }
    #pragma unroll
    for (int off = 32; off >= 1; off >>= 1) a += __shfl_xor(a, off);
    if (lane == 0) out[18432 + b*10 + j] = betas[b*10 + j] + (a + dsb[j]) * e_b;
  }
  if (w >= 1 && w < 4){
    int j = w - 1;
    float a = 0.f;
    #pragma unroll
    for (int i = 0; i < 4; ++i){
      int k = lane + 64*i;
      a += Os[0][k] * dcw[k*3 + j];
    }
    #pragma unroll
    for (int off = 32; off >= 1; off >>= 1) a += __shfl_xor(a, off);
    if (lane == 0) out[19712 + b*3 + j] = cam[b*3 + j] + (a + dcb[j]) * e_c;
  }
}

// ---------- launch ----------
extern "C" void kernel_launch(void* const* d_in, const int* in_sizes, int n_in,
                              void* d_out, int out_size, void* d_ws, size_t ws_size,
                              hipStream_t stream) {
  const float* img    = (const float*)d_in[0];
  const float* joints = (const float*)d_in[1];
  const float* pcam   = (const float*)d_in[2];
  const float* focal  = (const float*)d_in[3];
  const float* prot   = (const float*)d_in[4];
  const float* betas  = (const float*)d_in[5];
  const float* cam    = (const float*)d_in[6];
  const float* ln_g   = (const float*)d_in[7];
  const float* ln_b   = (const float*)d_in[8];
  const float* wk     = (const float*)d_in[9];
  const float* bk     = (const float*)d_in[10];
  const float* wv     = (const float*)d_in[11];
  const float* bv     = (const float*)d_in[12];
  const float* jw1    = (const float*)d_in[13];
  const float* jb1    = (const float*)d_in[14];
  const float* jw2    = (const float*)d_in[15];
  const float* jb2    = (const float*)d_in[16];
  const float* jid    = (const float*)d_in[17];
  const float* wq     = (const float*)d_in[18];
  const float* bq     = (const float*)d_in[19];
  const float* wo     = (const float*)d_in[20];
  const float* bo     = (const float*)d_in[21];
  const float* ng     = (const float*)d_in[22];
  const float* nb     = (const float*)d_in[23];
  const float* dpw    = (const float*)d_in[24];
  const float* dpb    = (const float*)d_in[25];
  const float* dsw    = (const float*)d_in[26];
  const float* dsb    = (const float*)d_in[27];
  const float* dcw    = (const float*)d_in[28];
  const float* dcb    = (const float*)d_in[29];
  const float* pls    = (const float*)d_in[30];
  const float* bls    = (const float*)d_in[31];
  const float* cls    = (const float*)d_in[32];

  // Fixed region (9,004,032 B), then batch-chunked Kt/Vt (bf16).
  char* ws = (char*)d_ws;
  float*         uvP = (float*)(ws + 0);                 //    65,536
  float*         u   = (float*)(ws + 65536);             //     2,048
  float*         v   = (float*)(ws + 67584);             //     2,048
  unsigned char* Wb  = (unsigned char*)(ws + 69632);     //   655,360
  float*         Jf  = (float*)(ws + 724992);            // 2,752,512
  float*         Qw  = (float*)(ws + 3477504);           // 2,752,512
  float*         J2  = (float*)(ws + 6230016);           //    21,504
  float*         AO  = (float*)(ws + 6251520);           // 2,752,512
  const size_t FIXED = 9004032;

  // chunked: Kt 16,777,216 + Vt 16,777,216 (bf16, full batch)
  int NC = 16;
  for (int c = 1; c <= 16; c <<= 1){
    size_t need = FIXED + (size_t)33554432 / c;
    if (need <= ws_size){ NC = c; break; }
  }
  int Bc = 128 / NC;
  size_t kv_bytes = (size_t)16777216 / NC;
  unsigned short* Kt = (unsigned short*)(ws + FIXED);
  unsigned short* Vt = (unsigned short*)(ws + FIXED + kv_bytes);

  float* out = (float*)d_out;  // f32 outputs

  prep_w <<<16,  512, 0, stream>>>(wk, wv, ln_g, ln_b, Wb, uvP);
  jointk <<<128, 1024, 0, stream>>>(joints, pcam, focal, jw1, jb1, jw2, jb2, jid, wq, bq,
                                    uvP, bk, bv, u, v, Jf, Qw, J2);
  for (int c = 0; c < NC; ++c){
    int b0 = c * Bc;
    gemm_kv <<<Bc*4, 512, 0, stream>>>(Wb, img, u, v, Kt, Vt, b0);
    attnk   <<<Bc*4, 256, 0, stream>>>(Qw, Kt, Vt, J2, AO, b0);
  }
  headk  <<<128, 1024, 0, stream>>>(AO, Jf, wo, bo, ng, nb, dpw, dpb, dsw, dsb, dcw, dcb, pls, bls, cls, prot, betas, cam, out);
}